// Round 1
// baseline (763.531 us; speedup 1.0000x reference)
//
#include <hip/hip_runtime.h>

// Problem constants (fixed instance from setup_inputs)
#define NB 2
#define LD 4800      // h0*w0
#define SD 4800      // h1*w1
#define CD 256
#define H0 60
#define W0 80
#define H1 60
#define W1 80
#define MG 2
#define THRESH 0.2f
#define SIM_SCALE (1.0f / (256.0f * 0.1f))   // 1/(C*TEMP)

typedef float f32x4 __attribute__((ext_vector_type(4)));
typedef __bf16 bf16x8 __attribute__((ext_vector_type(8)));
typedef unsigned short u16x8 __attribute__((ext_vector_type(8)));

__device__ __forceinline__ unsigned short f2bf(float f) {
    // round-to-nearest-even fp32 -> bf16 (inputs are finite normals)
    unsigned int u = __float_as_uint(f);
    u = u + 0x7FFFu + ((u >> 16) & 1u);
    return (unsigned short)(u >> 16);
}

__device__ __forceinline__ bool interior0(int idx) {
    int i = idx / W0, j = idx % W0;
    return (i >= MG) & (i < H0 - MG) & (j >= MG) & (j < W0 - MG);
}
__device__ __forceinline__ bool interior1(int idx) {
    int i = idx / W1, j = idx % W1;
    return (i >= MG) & (i < H1 - MG) & (j >= MG) & (j < W1 - MG);
}

// ---------------------------------------------------------------- K0: zero ws
__global__ __launch_bounds__(256) void k_zero(float* __restrict__ p, int n) {
    int i = blockIdx.x * 256 + threadIdx.x;
    if (i < n) p[i] = 0.f;
}

// ------------------------------------------- K1: bf16 MFMA GEMM + exp-sums
// sim[n,l,s] = f0[n,l,:].f1[n,s,:] / 25.6 ; also rowsum[n,l]=sum_s exp(sim),
// colsum[n,s]=sum_l exp(sim). 128x128 tile, 4 waves (2x2), wave = 64x64.
__global__ __launch_bounds__(256) void k_gemm(const float* __restrict__ f0,
                                              const float* __restrict__ f1,
                                              float* __restrict__ sim,
                                              float* __restrict__ rowsum,
                                              float* __restrict__ colsum) {
    // +8 pad: b128 frag reads land 2 rows/bank-group (2-way = free, m136)
    __shared__ __align__(16) unsigned short As[128][40];
    __shared__ __align__(16) unsigned short Bs[128][40];

    const int n  = blockIdx.z;
    const int s0 = blockIdx.x * 128;
    const int l0 = blockIdx.y * 128;
    const int tid  = threadIdx.x;
    const int lane = tid & 63;
    const int wave = tid >> 6;
    const int wm = (wave >> 1) * 64;   // wave row origin in tile
    const int wn = (wave & 1) * 64;    // wave col origin in tile
    const int quad = lane >> 4;
    const int lr   = lane & 15;

    f32x4 acc[4][4];
#pragma unroll
    for (int i = 0; i < 4; ++i)
#pragma unroll
        for (int j = 0; j < 4; ++j) acc[i][j] = (f32x4){0.f, 0.f, 0.f, 0.f};

    // staging role: thread -> (row r, 16-col half c0)
    const int r  = tid >> 1;
    const int c0 = (tid & 1) * 16;
    const bool a_ok = (l0 + r) < LD;
    const bool b_ok = (s0 + r) < SD;
    const float* aptr = f0 + ((size_t)n * LD + (a_ok ? (l0 + r) : 0)) * CD + c0;
    const float* bptr = f1 + ((size_t)n * SD + (b_ok ? (s0 + r) : 0)) * CD + c0;

    for (int k0 = 0; k0 < CD; k0 += 32) {
        __syncthreads();   // previous tile fully consumed
        float4 da[4], db[4];
#pragma unroll
        for (int v = 0; v < 4; ++v) {
            da[v] = a_ok ? *(const float4*)(aptr + k0 + 4 * v) : make_float4(0, 0, 0, 0);
            db[v] = b_ok ? *(const float4*)(bptr + k0 + 4 * v) : make_float4(0, 0, 0, 0);
        }
        u16x8 va0 = {f2bf(da[0].x), f2bf(da[0].y), f2bf(da[0].z), f2bf(da[0].w),
                     f2bf(da[1].x), f2bf(da[1].y), f2bf(da[1].z), f2bf(da[1].w)};
        u16x8 va1 = {f2bf(da[2].x), f2bf(da[2].y), f2bf(da[2].z), f2bf(da[2].w),
                     f2bf(da[3].x), f2bf(da[3].y), f2bf(da[3].z), f2bf(da[3].w)};
        u16x8 vb0 = {f2bf(db[0].x), f2bf(db[0].y), f2bf(db[0].z), f2bf(db[0].w),
                     f2bf(db[1].x), f2bf(db[1].y), f2bf(db[1].z), f2bf(db[1].w)};
        u16x8 vb1 = {f2bf(db[2].x), f2bf(db[2].y), f2bf(db[2].z), f2bf(db[2].w),
                     f2bf(db[3].x), f2bf(db[3].y), f2bf(db[3].z), f2bf(db[3].w)};
        *(u16x8*)&As[r][c0]     = va0;
        *(u16x8*)&As[r][c0 + 8] = va1;
        *(u16x8*)&Bs[r][c0]     = vb0;
        *(u16x8*)&Bs[r][c0 + 8] = vb1;
        __syncthreads();

        bf16x8 af[4], bfr[4];
#pragma unroll
        for (int i = 0; i < 4; ++i) {
            af[i]  = __builtin_bit_cast(bf16x8, *(const u16x8*)&As[wm + i * 16 + lr][quad * 8]);
            bfr[i] = __builtin_bit_cast(bf16x8, *(const u16x8*)&Bs[wn + i * 16 + lr][quad * 8]);
        }
#pragma unroll
        for (int i = 0; i < 4; ++i)
#pragma unroll
            for (int j = 0; j < 4; ++j)
                acc[i][j] = __builtin_amdgcn_mfma_f32_16x16x32_bf16(af[i], bfr[j], acc[i][j], 0, 0, 0);
    }

    // epilogue: C/D layout col=lane&15, row=quad*4+reg (m89)
    const int rb = l0 + wm;
    const int cb = s0 + wn;
    float rpart[4][4];   // [mi][reg] partial row sums over this wave's 64 cols
    float cpart[4];      // [ni]     partial col sums over this wave's 64 rows
#pragma unroll
    for (int i = 0; i < 4; ++i) {
        cpart[i] = 0.f;
#pragma unroll
        for (int g = 0; g < 4; ++g) rpart[i][g] = 0.f;
    }
#pragma unroll
    for (int mi = 0; mi < 4; ++mi)
#pragma unroll
        for (int ni = 0; ni < 4; ++ni)
#pragma unroll
            for (int g = 0; g < 4; ++g) {
                int row = rb + mi * 16 + quad * 4 + g;
                int col = cb + ni * 16 + lr;
                float sv = acc[mi][ni][g] * SIM_SCALE;
                bool ok = (row < LD) & (col < SD);
                float ev = ok ? __expf(sv) : 0.f;
                rpart[mi][g] += ev;
                cpart[ni] += ev;
                if (ok) sim[((size_t)n * LD + row) * SD + col] = sv;
            }
    // row sums: reduce over the 16 col-lanes (low 4 lane bits)
#pragma unroll
    for (int mi = 0; mi < 4; ++mi)
#pragma unroll
        for (int g = 0; g < 4; ++g) {
            float v = rpart[mi][g];
            v += __shfl_xor(v, 1);
            v += __shfl_xor(v, 2);
            v += __shfl_xor(v, 4);
            v += __shfl_xor(v, 8);
            int row = rb + mi * 16 + quad * 4 + g;
            if (lr == 0 && row < LD) atomicAdd(&rowsum[n * LD + row], v);
        }
    // col sums: reduce over the 4 quads (lane bits 4,5)
#pragma unroll
    for (int ni = 0; ni < 4; ++ni) {
        float v = cpart[ni];
        v += __shfl_xor(v, 16);
        v += __shfl_xor(v, 32);
        int col = cb + ni * 16 + lr;
        if (quad == 0 && col < SD) atomicAdd(&colsum[n * SD + col], v);
    }
}

// ---------------------- K2: conf = exp(2 sim)/(rowsum*colsum) in-place + rowmax
__global__ __launch_bounds__(256) void k_conf(float* __restrict__ conf,
                                              const float* __restrict__ rowsum,
                                              const float* __restrict__ colsum,
                                              float* __restrict__ rowmax) {
    const int l = blockIdx.x, n = blockIdx.y;
    const size_t base = ((size_t)n * LD + l) * SD;
    const float rinv = 1.0f / rowsum[n * LD + l];
    const float* cs = colsum + (size_t)n * SD;
    float m = 0.f;
    for (int s = threadIdx.x * 4; s < SD; s += 1024) {
        float4 sv = *(const float4*)(conf + base + s);
        float4 c4 = *(const float4*)(cs + s);
        float4 o;
        o.x = __expf(2.f * sv.x) * rinv / c4.x;
        o.y = __expf(2.f * sv.y) * rinv / c4.y;
        o.z = __expf(2.f * sv.z) * rinv / c4.z;
        o.w = __expf(2.f * sv.w) * rinv / c4.w;
        *(float4*)(conf + base + s) = o;
        m = fmaxf(m, fmaxf(fmaxf(o.x, o.y), fmaxf(o.z, o.w)));
    }
#pragma unroll
    for (int off = 32; off; off >>= 1) m = fmaxf(m, __shfl_xor(m, off));
    __shared__ float red[4];
    if ((threadIdx.x & 63) == 0) red[threadIdx.x >> 6] = m;
    __syncthreads();
    if (threadIdx.x == 0)
        rowmax[n * LD + l] = fmaxf(fmaxf(red[0], red[1]), fmaxf(red[2], red[3]));
}

// ---------------------------------- K3: column max (chunked, uint atomicMax)
__global__ __launch_bounds__(256) void k_colmax(const float* __restrict__ conf,
                                                unsigned int* __restrict__ colmax) {
    const int n = blockIdx.z;
    const int s = (blockIdx.x * 256 + threadIdx.x) * 4;
    if (s >= SD) return;
    const int l0 = blockIdx.y * 75;   // 64 chunks * 75 rows = 4800
    const float* p = conf + ((size_t)n * LD + l0) * SD + s;
    float4 m = {0.f, 0.f, 0.f, 0.f};
    for (int i = 0; i < 75; ++i) {
        float4 v = *(const float4*)(p + (size_t)i * SD);
        m.x = fmaxf(m.x, v.x);
        m.y = fmaxf(m.y, v.y);
        m.z = fmaxf(m.z, v.z);
        m.w = fmaxf(m.w, v.w);
    }
    unsigned int* c = colmax + (size_t)n * SD + s;
    // conf >= 0 so float bit pattern is monotone under uint compare
    atomicMax(c + 0, __float_as_uint(m.x));
    atomicMax(c + 1, __float_as_uint(m.y));
    atomicMax(c + 2, __float_as_uint(m.z));
    atomicMax(c + 3, __float_as_uint(m.w));
}

// --------------------------------------------- K4: mask + matched_conf write
__global__ __launch_bounds__(256) void k_final(const float* __restrict__ conf,
                                               const float* __restrict__ rowmax,
                                               const float* __restrict__ colmax,
                                               float* __restrict__ mask,
                                               float* __restrict__ matched) {
    const int l = blockIdx.x, n = blockIdx.y;
    const size_t base = ((size_t)n * LD + l) * SD;
    const bool v0 = interior0(l);
    const float rm = rowmax[n * LD + l];
    const float* cm = colmax + (size_t)n * SD;
    for (int s = threadIdx.x * 4; s < SD; s += 1024) {
        float4 c = *(const float4*)(conf + base + s);
        float4 x = *(const float4*)(cm + s);
        float4 mk, mt;
        {
            bool b = v0 & (c.x > THRESH) & interior1(s + 0) & (c.x == rm) & (c.x == x.x);
            mk.x = b ? 1.f : 0.f; mt.x = b ? c.x : 0.f;
        }
        {
            bool b = v0 & (c.y > THRESH) & interior1(s + 1) & (c.y == rm) & (c.y == x.y);
            mk.y = b ? 1.f : 0.f; mt.y = b ? c.y : 0.f;
        }
        {
            bool b = v0 & (c.z > THRESH) & interior1(s + 2) & (c.z == rm) & (c.z == x.z);
            mk.z = b ? 1.f : 0.f; mt.z = b ? c.z : 0.f;
        }
        {
            bool b = v0 & (c.w > THRESH) & interior1(s + 3) & (c.w == rm) & (c.w == x.w);
            mk.w = b ? 1.f : 0.f; mt.w = b ? c.w : 0.f;
        }
        *(float4*)(mask + base + s) = mk;
        *(float4*)(matched + base + s) = mt;
    }
}

extern "C" void kernel_launch(void* const* d_in, const int* in_sizes, int n_in,
                              void* d_out, int out_size, void* d_ws, size_t ws_size,
                              hipStream_t stream) {
    const float* f0 = (const float*)d_in[0];
    const float* f1 = (const float*)d_in[1];
    const size_t plane = (size_t)NB * LD * SD;
    float* conf = (float*)d_out;          // pass1 writes sim here, pass2 overwrites with conf
    float* mask = conf + plane;
    float* matched = mask + plane;

    float* rowsum = (float*)d_ws;                       // NB*LD
    float* colsum = rowsum + NB * LD;                   // NB*SD
    unsigned int* colmax = (unsigned int*)(colsum + NB * SD);  // NB*SD
    float* rowmax = (float*)(colmax + NB * SD);         // NB*LD (no init needed)

    // zero rowsum+colsum+colmax (contiguous 3*9600 floats)
    k_zero<<<dim3((NB * (LD + SD + SD) + 255) / 256), 256, 0, stream>>>(rowsum,
                                                                        NB * (LD + SD + SD));
    k_gemm<<<dim3((SD + 127) / 128, (LD + 127) / 128, NB), 256, 0, stream>>>(
        f0, f1, conf, rowsum, colsum);
    k_conf<<<dim3(LD, NB), 256, 0, stream>>>(conf, rowsum, colsum, rowmax);
    k_colmax<<<dim3(5, 64, NB), 256, 0, stream>>>(conf, colmax);
    k_final<<<dim3(LD, NB), 256, 0, stream>>>(conf, rowmax, (const float*)colmax, mask, matched);
}

// Round 2
// 716.084 us; speedup vs baseline: 1.0663x; 1.0663x over previous
//
#include <hip/hip_runtime.h>

// Problem constants (fixed instance from setup_inputs)
#define NB 2
#define LD 4800      // h0*w0
#define SD 4800      // h1*w1
#define CD 256
#define H0 60
#define W0 80
#define H1 60
#define W1 80
#define MG 2
#define THRESH 0.2f
#define SIM_SCALE (1.0f / (256.0f * 0.1f))   // 1/(C*TEMP)
#define GT 38        // ceil(4800/128)

typedef float f32x4 __attribute__((ext_vector_type(4)));
typedef __bf16 bf16x8 __attribute__((ext_vector_type(8)));
typedef unsigned short u16x8 __attribute__((ext_vector_type(8)));

#define GLOBAL_AS __attribute__((address_space(1)))
#define LDS_AS __attribute__((address_space(3)))

__device__ __forceinline__ void gl_lds16(const unsigned short* g, unsigned short* l) {
    // async global->LDS, 16 B/lane; LDS dest = wave-uniform base + lane*16
    __builtin_amdgcn_global_load_lds((const GLOBAL_AS unsigned int*)g,
                                     (LDS_AS unsigned int*)l, 16, 0, 0);
}

__device__ __forceinline__ unsigned short f2bf(float f) {
    // round-to-nearest-even fp32 -> bf16 (inputs are finite normals)
    unsigned int u = __float_as_uint(f);
    u = u + 0x7FFFu + ((u >> 16) & 1u);
    return (unsigned short)(u >> 16);
}

__device__ __forceinline__ bool interior0(int idx) {
    int i = idx / W0, j = idx % W0;
    return (i >= MG) & (i < H0 - MG) & (j >= MG) & (j < W0 - MG);
}
__device__ __forceinline__ bool interior1(int idx) {
    int i = idx / W1, j = idx % W1;
    return (i >= MG) & (i < H1 - MG) & (j >= MG) & (j < W1 - MG);
}

// ---------------------------------------------------------------- K0: zero ws
__global__ __launch_bounds__(256) void k_zero(float* __restrict__ p, int n) {
    int i = blockIdx.x * 256 + threadIdx.x;
    if (i < n) p[i] = 0.f;
}

// ------------------------------------------------- K1: fp32 -> bf16 convert
__global__ __launch_bounds__(256) void k_cvt(const float* __restrict__ src,
                                             unsigned short* __restrict__ dst, int n8) {
    int i = blockIdx.x * 256 + threadIdx.x;
    if (i >= n8) return;
    const float4* s = (const float4*)src + (size_t)i * 2;
    float4 a = s[0], b = s[1];
    u16x8 o = {f2bf(a.x), f2bf(a.y), f2bf(a.z), f2bf(a.w),
               f2bf(b.x), f2bf(b.y), f2bf(b.z), f2bf(b.w)};
    *(u16x8*)(dst + (size_t)i * 8) = o;
}

// -------------------------------------------------- K2/K3: bf16 MFMA GEMM
// PASS 0: accumulate rowsum[n,l]=sum_s exp(sim), colsum[n,s]=sum_l exp(sim)
// PASS 1: conf = exp(sim)^2 * rinv * cinv, write conf, atomicMax row/col maxes
// 128x128 tile, 4 waves (2x2), wave tile 64x64, 16x16x32 bf16 MFMA.
template <int PASS>
__global__ __launch_bounds__(256) void k_gemm(const unsigned short* __restrict__ bA,
                                              const unsigned short* __restrict__ bB,
                                              float* __restrict__ rowsum,
                                              float* __restrict__ colsum,
                                              float* __restrict__ conf,
                                              unsigned int* __restrict__ rowmax,
                                              unsigned int* __restrict__ colmax) {
    // no padding: global_load_lds lands lane i at base + 16*i (row-major [128][32])
    __shared__ __align__(16) unsigned short As[128][32];
    __shared__ __align__(16) unsigned short Bs[128][32];

    const int n  = blockIdx.z;
    const int s0 = blockIdx.x * 128;
    const int l0 = blockIdx.y * 128;
    const int tid  = threadIdx.x;
    const int lane = tid & 63;
    const int wave = tid >> 6;
    const int wm = (wave >> 1) * 64;
    const int wn = (wave & 1) * 64;
    const int quad = lane >> 4;
    const int lr   = lane & 15;

    // staging: wave w stages rows [w*32, w*32+32) of A and B, 2 instrs each;
    // lane i -> row +i/4, 16B chunk (i%4) within the 64B (32 x bf16) k-slice.
    const int sr = wave * 32 + (lane >> 2);
    const int sc = (lane & 3) * 8;
    // tail tiles (4800 = 37.5*128): clamp row (duplicate reads), guard in epilogue
    const unsigned short* ga0 = bA + ((size_t)n * LD + min(l0 + sr,      LD - 1)) * CD + sc;
    const unsigned short* ga1 = bA + ((size_t)n * LD + min(l0 + sr + 16, LD - 1)) * CD + sc;
    const unsigned short* gb0 = bB + ((size_t)n * SD + min(s0 + sr,      SD - 1)) * CD + sc;
    const unsigned short* gb1 = bB + ((size_t)n * SD + min(s0 + sr + 16, SD - 1)) * CD + sc;
    unsigned short* la0 = &As[wave * 32][0];
    unsigned short* la1 = &As[wave * 32 + 16][0];
    unsigned short* lb0 = &Bs[wave * 32][0];
    unsigned short* lb1 = &Bs[wave * 32 + 16][0];

    f32x4 acc[4][4];
#pragma unroll
    for (int i = 0; i < 4; ++i)
#pragma unroll
        for (int j = 0; j < 4; ++j) acc[i][j] = (f32x4){0.f, 0.f, 0.f, 0.f};

    for (int k0 = 0; k0 < CD; k0 += 32) {
        __syncthreads();   // previous tile fully consumed
        gl_lds16(ga0 + k0, la0);
        gl_lds16(ga1 + k0, la1);
        gl_lds16(gb0 + k0, lb0);
        gl_lds16(gb1 + k0, lb1);
        __syncthreads();   // compiler drains vmcnt before barrier

        bf16x8 af[4], bfr[4];
#pragma unroll
        for (int i = 0; i < 4; ++i) {
            af[i]  = __builtin_bit_cast(bf16x8, *(const u16x8*)&As[wm + i * 16 + lr][quad * 8]);
            bfr[i] = __builtin_bit_cast(bf16x8, *(const u16x8*)&Bs[wn + i * 16 + lr][quad * 8]);
        }
#pragma unroll
        for (int i = 0; i < 4; ++i)
#pragma unroll
            for (int j = 0; j < 4; ++j)
                acc[i][j] = __builtin_amdgcn_mfma_f32_16x16x32_bf16(af[i], bfr[j], acc[i][j], 0, 0, 0);
    }

    // epilogue: C/D layout col=lane&15, row=quad*4+reg (m89)
    const int rb = l0 + wm;
    const int cb = s0 + wn;

    if (PASS == 0) {
        float rpart[4][4];   // [mi][reg] partial row sums over this wave's 64 cols
        float cpart[4];      // [ni]     partial col sums over this wave's 64 rows
#pragma unroll
        for (int i = 0; i < 4; ++i) {
            cpart[i] = 0.f;
#pragma unroll
            for (int g = 0; g < 4; ++g) rpart[i][g] = 0.f;
        }
#pragma unroll
        for (int mi = 0; mi < 4; ++mi)
#pragma unroll
            for (int ni = 0; ni < 4; ++ni)
#pragma unroll
                for (int g = 0; g < 4; ++g) {
                    int row = rb + mi * 16 + quad * 4 + g;
                    int col = cb + ni * 16 + lr;
                    float sv = acc[mi][ni][g] * SIM_SCALE;
                    bool ok = (row < LD) & (col < SD);
                    float ev = ok ? __expf(sv) : 0.f;
                    rpart[mi][g] += ev;
                    cpart[ni] += ev;
                }
#pragma unroll
        for (int mi = 0; mi < 4; ++mi)
#pragma unroll
            for (int g = 0; g < 4; ++g) {
                float v = rpart[mi][g];
                v += __shfl_xor(v, 1);
                v += __shfl_xor(v, 2);
                v += __shfl_xor(v, 4);
                v += __shfl_xor(v, 8);
                int row = rb + mi * 16 + quad * 4 + g;
                if (lr == 0 && row < LD) atomicAdd(&rowsum[n * LD + row], v);
            }
#pragma unroll
        for (int ni = 0; ni < 4; ++ni) {
            float v = cpart[ni];
            v += __shfl_xor(v, 16);
            v += __shfl_xor(v, 32);
            int col = cb + ni * 16 + lr;
            if (quad == 0 && col < SD) atomicAdd(&colsum[n * SD + col], v);
        }
    } else {
        // per-lane reciprocal tables (16 rows, 4 cols touched by this lane)
        float rinv[4][4], cinv[4];
#pragma unroll
        for (int mi = 0; mi < 4; ++mi)
#pragma unroll
            for (int g = 0; g < 4; ++g) {
                int row = min(rb + mi * 16 + quad * 4 + g, LD - 1);
                rinv[mi][g] = 1.0f / rowsum[n * LD + row];
            }
#pragma unroll
        for (int ni = 0; ni < 4; ++ni) {
            int col = min(cb + ni * 16 + lr, SD - 1);
            cinv[ni] = 1.0f / colsum[n * SD + col];
        }
        float rmx[4][4], cmx[4];
#pragma unroll
        for (int i = 0; i < 4; ++i) {
            cmx[i] = 0.f;
#pragma unroll
            for (int g = 0; g < 4; ++g) rmx[i][g] = 0.f;
        }
#pragma unroll
        for (int mi = 0; mi < 4; ++mi)
#pragma unroll
            for (int ni = 0; ni < 4; ++ni)
#pragma unroll
                for (int g = 0; g < 4; ++g) {
                    int row = rb + mi * 16 + quad * 4 + g;
                    int col = cb + ni * 16 + lr;
                    float sv = acc[mi][ni][g] * SIM_SCALE;
                    float e = __expf(sv);
                    float cv = e * e * rinv[mi][g] * cinv[ni];
                    bool ok = (row < LD) & (col < SD);
                    if (ok) {
                        conf[((size_t)n * LD + row) * SD + col] = cv;
                        rmx[mi][g] = fmaxf(rmx[mi][g], cv);
                        cmx[ni]    = fmaxf(cmx[ni], cv);
                    }
                }
#pragma unroll
        for (int mi = 0; mi < 4; ++mi)
#pragma unroll
            for (int g = 0; g < 4; ++g) {
                float v = rmx[mi][g];
                v = fmaxf(v, __shfl_xor(v, 1));
                v = fmaxf(v, __shfl_xor(v, 2));
                v = fmaxf(v, __shfl_xor(v, 4));
                v = fmaxf(v, __shfl_xor(v, 8));
                int row = rb + mi * 16 + quad * 4 + g;
                if (lr == 0 && row < LD)
                    atomicMax(&rowmax[n * LD + row], __float_as_uint(v));
            }
#pragma unroll
        for (int ni = 0; ni < 4; ++ni) {
            float v = cmx[ni];
            v = fmaxf(v, __shfl_xor(v, 16));
            v = fmaxf(v, __shfl_xor(v, 32));
            int col = cb + ni * 16 + lr;
            if (quad == 0 && col < SD)
                atomicMax(&colmax[n * SD + col], __float_as_uint(v));
        }
    }
}

// --------------------------------------------- K4: mask + matched_conf write
__global__ __launch_bounds__(256) void k_final(const float* __restrict__ conf,
                                               const float* __restrict__ rowmax,
                                               const float* __restrict__ colmax,
                                               float* __restrict__ mask,
                                               float* __restrict__ matched) {
    const int l = blockIdx.x, n = blockIdx.y;
    const size_t base = ((size_t)n * LD + l) * SD;
    const bool v0 = interior0(l);
    const float rm = rowmax[n * LD + l];
    const float* cm = colmax + (size_t)n * SD;
    for (int s = threadIdx.x * 4; s < SD; s += 1024) {
        float4 c = *(const float4*)(conf + base + s);
        float4 x = *(const float4*)(cm + s);
        float4 mk, mt;
        {
            bool b = v0 & (c.x > THRESH) & interior1(s + 0) & (c.x == rm) & (c.x == x.x);
            mk.x = b ? 1.f : 0.f; mt.x = b ? c.x : 0.f;
        }
        {
            bool b = v0 & (c.y > THRESH) & interior1(s + 1) & (c.y == rm) & (c.y == x.y);
            mk.y = b ? 1.f : 0.f; mt.y = b ? c.y : 0.f;
        }
        {
            bool b = v0 & (c.z > THRESH) & interior1(s + 2) & (c.z == rm) & (c.z == x.z);
            mk.z = b ? 1.f : 0.f; mt.z = b ? c.z : 0.f;
        }
        {
            bool b = v0 & (c.w > THRESH) & interior1(s + 3) & (c.w == rm) & (c.w == x.w);
            mk.w = b ? 1.f : 0.f; mt.w = b ? c.w : 0.f;
        }
        *(float4*)(mask + base + s) = mk;
        *(float4*)(matched + base + s) = mt;
    }
}

extern "C" void kernel_launch(void* const* d_in, const int* in_sizes, int n_in,
                              void* d_out, int out_size, void* d_ws, size_t ws_size,
                              hipStream_t stream) {
    const float* f0 = (const float*)d_in[0];
    const float* f1 = (const float*)d_in[1];
    const size_t plane = (size_t)NB * LD * SD;
    float* conf = (float*)d_out;
    float* mask = conf + plane;
    float* matched = mask + plane;

    // ws layout (contiguous so one zero pass covers all): rowsum, colsum, rowmax, colmax
    float* rowsum = (float*)d_ws;                        // NB*LD
    float* colsum = rowsum + NB * LD;                    // NB*SD
    unsigned int* rowmaxu = (unsigned int*)(colsum + NB * SD);  // NB*LD
    unsigned int* colmaxu = rowmaxu + NB * LD;           // NB*SD

    // bf16 copies of the inputs, stashed in the mask output plane (184 MB;
    // k_final overwrites it last, after both GEMM passes have consumed them)
    unsigned short* bf0 = (unsigned short*)mask;
    unsigned short* bf1 = bf0 + (size_t)NB * LD * CD;

    const int nstat = NB * (LD + SD + LD + SD);
    k_zero<<<dim3((nstat + 255) / 256), 256, 0, stream>>>(rowsum, nstat);
    const int n8 = NB * LD * CD / 8;
    k_cvt<<<dim3((n8 + 255) / 256), 256, 0, stream>>>(f0, bf0, n8);
    k_cvt<<<dim3((n8 + 255) / 256), 256, 0, stream>>>(f1, bf1, n8);

    dim3 gg(GT, GT, NB);
    k_gemm<0><<<gg, 256, 0, stream>>>(bf0, bf1, rowsum, colsum, nullptr, nullptr, nullptr);
    k_gemm<1><<<gg, 256, 0, stream>>>(bf0, bf1, rowsum, colsum, conf, rowmaxu, colmaxu);
    k_final<<<dim3(LD, NB), 256, 0, stream>>>(conf, (const float*)rowmaxu,
                                              (const float*)colmaxu, mask, matched);
}

// Round 3
// 689.829 us; speedup vs baseline: 1.1068x; 1.0381x over previous
//
#include <hip/hip_runtime.h>

// Problem constants (fixed instance from setup_inputs)
#define NB 2
#define LD 4800      // h0*w0
#define SD 4800      // h1*w1
#define CD 256
#define H0 60
#define W0 80
#define H1 60
#define W1 80
#define MG 2
#define THRESH 0.2f
#define SIM_SCALE (1.0f / (256.0f * 0.1f))   // 1/(C*TEMP)
#define GT 38        // ceil(4800/128)
#define CAP 8192     // candidate-list capacity (elements with conf > THRESH)

typedef float f32x4 __attribute__((ext_vector_type(4)));
typedef __bf16 bf16x8 __attribute__((ext_vector_type(8)));
typedef unsigned short u16x8 __attribute__((ext_vector_type(8)));

#define GLOBAL_AS __attribute__((address_space(1)))
#define LDS_AS __attribute__((address_space(3)))

__device__ __forceinline__ void gl_lds16(const unsigned short* g, unsigned short* l) {
    // async global->LDS, 16 B/lane; LDS dest = wave-uniform base + lane*16
    __builtin_amdgcn_global_load_lds((const GLOBAL_AS unsigned int*)g,
                                     (LDS_AS unsigned int*)l, 16, 0, 0);
}

__device__ __forceinline__ unsigned short f2bf(float f) {
    // round-to-nearest-even fp32 -> bf16 (inputs are finite normals)
    unsigned int u = __float_as_uint(f);
    u = u + 0x7FFFu + ((u >> 16) & 1u);
    return (unsigned short)(u >> 16);
}

__device__ __forceinline__ bool interior0(int idx) {
    int i = idx / W0, j = idx % W0;
    return (i >= MG) & (i < H0 - MG) & (j >= MG) & (j < W0 - MG);
}
__device__ __forceinline__ bool interior1(int idx) {
    int i = idx / W1, j = idx % W1;
    return (i >= MG) & (i < H1 - MG) & (j >= MG) & (j < W1 - MG);
}

// ------------------------------------------------- K0: zero stats + counter
__global__ __launch_bounds__(256) void k_prep(float* __restrict__ p, int n) {
    int i = blockIdx.x * 256 + threadIdx.x;
    if (i < n) p[i] = 0.f;
}

// ------------------------------------------------- K1: fp32 -> bf16 convert
__global__ __launch_bounds__(256) void k_cvt(const float* __restrict__ src,
                                             unsigned short* __restrict__ dst, int n8) {
    int i = blockIdx.x * 256 + threadIdx.x;
    if (i >= n8) return;
    const float4* s = (const float4*)src + (size_t)i * 2;
    float4 a = s[0], b = s[1];
    u16x8 o = {f2bf(a.x), f2bf(a.y), f2bf(a.z), f2bf(a.w),
               f2bf(b.x), f2bf(b.y), f2bf(b.z), f2bf(b.w)};
    *(u16x8*)(dst + (size_t)i * 8) = o;
}

// -------------------------------------------------- K2/K3: bf16 MFMA GEMM
// PASS 0: accumulate rowsum[n,l]=sum_s exp(sim), colsum[n,s]=sum_l exp(sim)
// PASS 1: conf = exp(sim)^2*rinv*cinv -> conf plane; elements > THRESH (rare)
//         feed predicated atomicMax row/col maxes + an append-list.
//         (c>T & c==max  <=>  c>T & c==max-over-{>T}  -- so sparse maxes ok)
// 128x128 tile, 4 waves (2x2), wave tile 64x64, 16x16x32 bf16 MFMA.
template <int PASS>
__global__ __launch_bounds__(256) void k_gemm(const unsigned short* __restrict__ bA,
                                              const unsigned short* __restrict__ bB,
                                              float* __restrict__ rowsum,
                                              float* __restrict__ colsum,
                                              float* __restrict__ conf,
                                              unsigned int* __restrict__ rowmax,
                                              unsigned int* __restrict__ colmax,
                                              unsigned int* __restrict__ cnt,
                                              uint4* __restrict__ list) {
    // no padding: global_load_lds lands lane i at base + 16*i (row-major [128][32])
    __shared__ __align__(16) unsigned short As[128][32];
    __shared__ __align__(16) unsigned short Bs[128][32];

    const int n  = blockIdx.z;
    const int s0 = blockIdx.x * 128;
    const int l0 = blockIdx.y * 128;
    const int tid  = threadIdx.x;
    const int lane = tid & 63;
    const int wave = tid >> 6;
    const int wm = (wave >> 1) * 64;
    const int wn = (wave & 1) * 64;
    const int quad = lane >> 4;
    const int lr   = lane & 15;

    // staging: wave w stages rows [w*32, w*32+32) of A and B, 2 instrs each;
    // lane i -> row +i/4, 16B chunk (i%4) within the 64B (32 x bf16) k-slice.
    const int sr = wave * 32 + (lane >> 2);
    const int sc = (lane & 3) * 8;
    // tail tiles (4800 = 37.5*128): clamp row (duplicate reads), guard in epilogue
    const unsigned short* ga0 = bA + ((size_t)n * LD + min(l0 + sr,      LD - 1)) * CD + sc;
    const unsigned short* ga1 = bA + ((size_t)n * LD + min(l0 + sr + 16, LD - 1)) * CD + sc;
    const unsigned short* gb0 = bB + ((size_t)n * SD + min(s0 + sr,      SD - 1)) * CD + sc;
    const unsigned short* gb1 = bB + ((size_t)n * SD + min(s0 + sr + 16, SD - 1)) * CD + sc;
    unsigned short* la0 = &As[wave * 32][0];
    unsigned short* la1 = &As[wave * 32 + 16][0];
    unsigned short* lb0 = &Bs[wave * 32][0];
    unsigned short* lb1 = &Bs[wave * 32 + 16][0];

    f32x4 acc[4][4];
#pragma unroll
    for (int i = 0; i < 4; ++i)
#pragma unroll
        for (int j = 0; j < 4; ++j) acc[i][j] = (f32x4){0.f, 0.f, 0.f, 0.f};

    for (int k0 = 0; k0 < CD; k0 += 32) {
        __syncthreads();   // previous tile fully consumed
        gl_lds16(ga0 + k0, la0);
        gl_lds16(ga1 + k0, la1);
        gl_lds16(gb0 + k0, lb0);
        gl_lds16(gb1 + k0, lb1);
        __syncthreads();   // compiler drains vmcnt before barrier

        bf16x8 af[4], bfr[4];
#pragma unroll
        for (int i = 0; i < 4; ++i) {
            af[i]  = __builtin_bit_cast(bf16x8, *(const u16x8*)&As[wm + i * 16 + lr][quad * 8]);
            bfr[i] = __builtin_bit_cast(bf16x8, *(const u16x8*)&Bs[wn + i * 16 + lr][quad * 8]);
        }
#pragma unroll
        for (int i = 0; i < 4; ++i)
#pragma unroll
            for (int j = 0; j < 4; ++j)
                acc[i][j] = __builtin_amdgcn_mfma_f32_16x16x32_bf16(af[i], bfr[j], acc[i][j], 0, 0, 0);
    }

    // epilogue: C/D layout col=lane&15, row=quad*4+reg (m89)
    const int rb = l0 + wm;
    const int cb = s0 + wn;

    if (PASS == 0) {
        float rpart[4][4];   // [mi][reg] partial row sums over this wave's 64 cols
        float cpart[4];      // [ni]     partial col sums over this wave's 64 rows
#pragma unroll
        for (int i = 0; i < 4; ++i) {
            cpart[i] = 0.f;
#pragma unroll
            for (int g = 0; g < 4; ++g) rpart[i][g] = 0.f;
        }
#pragma unroll
        for (int mi = 0; mi < 4; ++mi)
#pragma unroll
            for (int ni = 0; ni < 4; ++ni)
#pragma unroll
                for (int g = 0; g < 4; ++g) {
                    int row = rb + mi * 16 + quad * 4 + g;
                    int col = cb + ni * 16 + lr;
                    float sv = acc[mi][ni][g] * SIM_SCALE;
                    bool ok = (row < LD) & (col < SD);
                    float ev = ok ? __expf(sv) : 0.f;
                    rpart[mi][g] += ev;
                    cpart[ni] += ev;
                }
#pragma unroll
        for (int mi = 0; mi < 4; ++mi)
#pragma unroll
            for (int g = 0; g < 4; ++g) {
                float v = rpart[mi][g];
                v += __shfl_xor(v, 1);
                v += __shfl_xor(v, 2);
                v += __shfl_xor(v, 4);
                v += __shfl_xor(v, 8);
                int row = rb + mi * 16 + quad * 4 + g;
                if (lr == 0 && row < LD) atomicAdd(&rowsum[n * LD + row], v);
            }
#pragma unroll
        for (int ni = 0; ni < 4; ++ni) {
            float v = cpart[ni];
            v += __shfl_xor(v, 16);
            v += __shfl_xor(v, 32);
            int col = cb + ni * 16 + lr;
            if (quad == 0 && col < SD) atomicAdd(&colsum[n * SD + col], v);
        }
    } else {
        float rinv[4][4], cinv[4];
#pragma unroll
        for (int mi = 0; mi < 4; ++mi)
#pragma unroll
            for (int g = 0; g < 4; ++g) {
                int row = min(rb + mi * 16 + quad * 4 + g, LD - 1);
                rinv[mi][g] = 1.0f / rowsum[n * LD + row];
            }
#pragma unroll
        for (int ni = 0; ni < 4; ++ni) {
            int col = min(cb + ni * 16 + lr, SD - 1);
            cinv[ni] = 1.0f / colsum[n * SD + col];
        }
#pragma unroll
        for (int mi = 0; mi < 4; ++mi)
#pragma unroll
            for (int ni = 0; ni < 4; ++ni)
#pragma unroll
                for (int g = 0; g < 4; ++g) {
                    int row = rb + mi * 16 + quad * 4 + g;
                    int col = cb + ni * 16 + lr;
                    float sv = acc[mi][ni][g] * SIM_SCALE;
                    float e = __expf(sv);
                    float cv = e * e * rinv[mi][g] * cinv[ni];
                    bool ok = (row < LD) & (col < SD);
                    if (ok) {
                        conf[((size_t)n * LD + row) * SD + col] = cv;
                        if (cv > THRESH) {   // rare: predicated maxes + append
                            atomicMax(&rowmax[n * LD + row], __float_as_uint(cv));
                            atomicMax(&colmax[n * SD + col], __float_as_uint(cv));
                            unsigned int id = atomicAdd(cnt, 1u);
                            if (id < CAP) {
                                uint4 rec = {(unsigned)n, (unsigned)row, (unsigned)col,
                                             __float_as_uint(cv)};
                                list[id] = rec;
                            }
                        }
                    }
                }
    }
}

// ----------------------------------- K4: zero-fill mask+matched (streaming)
__global__ __launch_bounds__(256) void k_fillz(float4* __restrict__ p, size_t n4) {
    size_t i = (size_t)blockIdx.x * 256 + threadIdx.x;
    const size_t stride = (size_t)gridDim.x * 256;
    const float4 z = {0.f, 0.f, 0.f, 0.f};
    for (; i < n4; i += stride) p[i] = z;
}

// ------------------------- K5: fixup the (rare) candidates into mask/matched
__global__ __launch_bounds__(256) void k_fix(const unsigned int* __restrict__ cnt,
                                             const uint4* __restrict__ list,
                                             const unsigned int* __restrict__ rowmax,
                                             const unsigned int* __restrict__ colmax,
                                             float* __restrict__ mask,
                                             float* __restrict__ matched) {
    unsigned int m = min(*cnt, (unsigned int)CAP);
    for (unsigned int i = threadIdx.x; i < m; i += 256) {
        uint4 r = list[i];
        int n = (int)r.x, row = (int)r.y, col = (int)r.z;
        unsigned int cb = r.w;   // bit pattern of cv (same bits as stored conf)
        if (cb == rowmax[n * LD + row] && cb == colmax[n * SD + col] &&
            interior0(row) && interior1(col)) {
            size_t o = ((size_t)n * LD + row) * SD + col;
            mask[o] = 1.f;
            matched[o] = __uint_as_float(cb);
        }
    }
}

extern "C" void kernel_launch(void* const* d_in, const int* in_sizes, int n_in,
                              void* d_out, int out_size, void* d_ws, size_t ws_size,
                              hipStream_t stream) {
    const float* f0 = (const float*)d_in[0];
    const float* f1 = (const float*)d_in[1];
    const size_t plane = (size_t)NB * LD * SD;
    float* conf = (float*)d_out;
    float* mask = conf + plane;      // mask + matched are contiguous (2*plane)

    // ws layout (evidence: harness re-poison fills are 2.21 GB -> ws is GB-scale):
    // [rowsum NB*LD][colsum NB*SD][rowmaxu NB*LD][colmaxu NB*SD][cnt 4xu32]
    // [list CAP*uint4][bf0][bf1]
    float* rowsum = (float*)d_ws;
    float* colsum = rowsum + NB * LD;
    unsigned int* rowmaxu = (unsigned int*)(colsum + NB * SD);
    unsigned int* colmaxu = rowmaxu + NB * LD;
    unsigned int* cnt = colmaxu + NB * SD;               // 4 uints (1 used)
    uint4* list = (uint4*)(cnt + 4);
    unsigned short* bf0 = (unsigned short*)(list + CAP);
    unsigned short* bf1 = bf0 + (size_t)NB * LD * CD;

    // zero stats + counter (contiguous: 4*9600 floats + 4 uints)
    const int nz = NB * (LD + SD) * 2 + 4;
    k_prep<<<dim3((nz + 255) / 256), 256, 0, stream>>>(rowsum, nz);
    const int n8 = NB * LD * CD / 8;
    k_cvt<<<dim3((n8 + 255) / 256), 256, 0, stream>>>(f0, bf0, n8);
    k_cvt<<<dim3((n8 + 255) / 256), 256, 0, stream>>>(f1, bf1, n8);

    dim3 gg(GT, GT, NB);
    k_gemm<0><<<gg, 256, 0, stream>>>(bf0, bf1, rowsum, colsum, nullptr,
                                      nullptr, nullptr, nullptr, nullptr);
    k_gemm<1><<<gg, 256, 0, stream>>>(bf0, bf1, rowsum, colsum, conf,
                                      rowmaxu, colmaxu, cnt, list);
    // mask+matched: streaming zero fill, then sparse fixup from the list
    k_fillz<<<dim3(4096), 256, 0, stream>>>((float4*)mask, 2 * plane / 4);
    k_fix<<<dim3(1), 256, 0, stream>>>(cnt, list, rowmaxu, colmaxu, mask, mask + plane);
}